// Round 3
// baseline (138.505 us; speedup 1.0000x reference)
//
#include <hip/hip_runtime.h>
#include <hip/hip_bf16.h>

typedef __bf16 bf16_8 __attribute__((ext_vector_type(8)));
typedef float  f32x4  __attribute__((ext_vector_type(4)));

#define N_TOK 1024
#define C_IN  128
#define H1D   128
#define H2D   64
#define NBAT  2
#define AR_STRIDE 256
#define AR_BYTES (NBAT * N_TOK * AR_STRIDE * 4)

// ---------------------------------------------------------------------------
// Kernel 1: ar[m][h'] for m in [0,2048), h' in [0,256):
//   h' <  128 : a'[m][h'] = x[m] @ W1[0:128, h']  + b1[h']   (b1 folded in)
//   h' >= 128 : r [m][h'-128] = x[m] @ W1[128:256, h'-128]
// ---------------------------------------------------------------------------
__global__ __launch_bounds__(256) void prep_ar_kernel(
    const float* __restrict__ x, const float* __restrict__ W1,
    const float* __restrict__ b1, float* __restrict__ ar)
{
    const int m0 = blockIdx.x * 32;
    const int h0 = blockIdx.y * 64;
    __shared__ float xs[32 * 132];
    __shared__ float wsh[128 * 64];
    const int t = threadIdx.x;

    #pragma unroll
    for (int it = 0; it < 4; ++it) {
        int f = t + it * 256;
        int row = f >> 5, c4 = f & 31;
        f32x4 v = *(const f32x4*)(x + (m0 + row) * C_IN + c4 * 4);
        *(f32x4*)(xs + row * 132 + c4 * 4) = v;
    }
    const float* wsrc = (h0 < 128) ? (W1 + h0) : (W1 + 128 * H1D + (h0 - 128));
    #pragma unroll
    for (int it = 0; it < 8; ++it) {
        int f = t + it * 256;
        int k = f >> 4, c4 = f & 15;
        f32x4 v = *(const f32x4*)(wsrc + k * H1D + c4 * 4);
        *(f32x4*)(wsh + k * 64 + c4 * 4) = v;
    }
    __syncthreads();

    const int tx = t & 15, ty = t >> 4;
    const int r0 = ty * 2, r1 = r0 + 1;
    float acc0[4] = {0.f, 0.f, 0.f, 0.f};
    float acc1[4] = {0.f, 0.f, 0.f, 0.f};
    #pragma unroll 4
    for (int k = 0; k < 128; ++k) {
        f32x4 w = *(const f32x4*)(wsh + k * 64 + tx * 4);
        float x0 = xs[r0 * 132 + k];
        float x1 = xs[r1 * 132 + k];
        #pragma unroll
        for (int c = 0; c < 4; ++c) {
            acc0[c] = fmaf(x0, w[c], acc0[c]);
            acc1[c] = fmaf(x1, w[c], acc1[c]);
        }
    }
    f32x4 bv = {0.f, 0.f, 0.f, 0.f};
    if (h0 < 128) bv = *(const f32x4*)(b1 + h0 + tx * 4);
    f32x4 o0, o1;
    #pragma unroll
    for (int c = 0; c < 4; ++c) { o0[c] = acc0[c] + bv[c]; o1[c] = acc1[c] + bv[c]; }
    *(f32x4*)(ar + (m0 + r0) * AR_STRIDE + h0 + tx * 4) = o0;
    *(f32x4*)(ar + (m0 + r1) * AR_STRIDE + h0 + tx * 4) = o1;
}

// ---------------------------------------------------------------------------
// Kernel 2: W2 (fp32 [128][64]) -> bf16 B-fragments for mfma_f32_16x16x32_bf16
// frag layout: [f = ks*4+nt][lane][jj]  with  k = ks*32 + (lane>>4)*8 + jj,
//                                            g = nt*16 + (lane&15)
// ---------------------------------------------------------------------------
__global__ __launch_bounds__(256) void prep_frags_kernel(
    const float* __restrict__ W2, __bf16* __restrict__ frag)
{
    int e = blockIdx.x * 256 + threadIdx.x;  // 0..1023
    int f = e >> 6, l = e & 63;
    int ks = f >> 2, nt = f & 3;
    int kbase = ks * 32 + (l >> 4) * 8;
    int g = nt * 16 + (l & 15);
    bf16_8 v;
    #pragma unroll
    for (int jj = 0; jj < 8; ++jj)
        v[jj] = (__bf16)(W2[(kbase + jj) * H2D + g]);
    *(bf16_8*)(frag + e * 8) = v;
}

// DPP butterfly add over the 16-lane DPP row (reduction over jl in [0,16)).
template <int CTRL>
__device__ __forceinline__ float dpp_add(float s) {
    int t = __builtin_amdgcn_update_dpp(0, __builtin_bit_cast(int, s),
                                        CTRL, 0xF, 0xF, true);
    return s + __builtin_bit_cast(float, t);
}
__device__ __forceinline__ float row16_reduce(float s) {
    s = dpp_add<0xB1>(s);   // quad_perm [1,0,3,2]  : xor 1
    s = dpp_add<0x4E>(s);   // quad_perm [2,3,0,1]  : xor 2
    s = dpp_add<0x141>(s);  // row_half_mirror      : merge quads within 8
    s = dpp_add<0x140>(s);  // row_mirror           : merge halves of 16
    return s;
}

// ---------------------------------------------------------------------------
// Kernel 3: main pair-MLP. Block = 64 i-rows x 16 j-cols, 4 waves.
// In-loop LDS traffic = ZERO: a' rows read from global (16-lane broadcast,
// L1/L2 resident), r + W2-frags in registers, reduction via DPP.
// ---------------------------------------------------------------------------
__global__ __launch_bounds__(256) void pair_mlp_kernel(
    const float* __restrict__ ar, const __bf16* __restrict__ frag,
    const float* __restrict__ b2, const float* __restrict__ W3,
    const float* __restrict__ b3, float* __restrict__ out)
{
    const int j0 = blockIdx.x * 16;   // 64 j-tiles
    const int i0 = blockIdx.y * 64;   // 16 i-tiles
    const int b  = blockIdx.z;
    const int t  = threadIdx.x;
    float* outb = out + (size_t)b * N_TOK * N_TOK;

    if (j0 + 15 <= i0) {
        // fully masked tile: write zeros (out is poisoned 0xAA)
        int row = t >> 2, q4 = t & 3;
        f32x4 z = {0.f, 0.f, 0.f, 0.f};
        *(f32x4*)(outb + (i0 + row) * N_TOK + j0 + q4 * 4) = z;
        return;
    }

    __shared__ float rLDS[16 * 132];  // r rows j0..j0+15, pad +4
    const float* arb = ar + (size_t)b * N_TOK * AR_STRIDE;
    if (t < 128) {
        int row = t >> 3, c4 = t & 7;
        *(f32x4*)(rLDS + row * 132 + c4 * 16) =
            *(const f32x4*)(arb + (j0 + row) * AR_STRIDE + 128 + c4 * 16);
        *(f32x4*)(rLDS + row * 132 + c4 * 16 + 4) =
            *(const f32x4*)(arb + (j0 + row) * AR_STRIDE + 128 + c4 * 16 + 4);
        *(f32x4*)(rLDS + row * 132 + c4 * 16 + 8) =
            *(const f32x4*)(arb + (j0 + row) * AR_STRIDE + 128 + c4 * 16 + 8);
        *(f32x4*)(rLDS + row * 132 + c4 * 16 + 12) =
            *(const f32x4*)(arb + (j0 + row) * AR_STRIDE + 128 + c4 * 16 + 12);
    }
    __syncthreads();

    const int lane = t & 63, w = t >> 6;
    const int q = lane >> 4, jl = lane & 15;

    // r regs: rr[ks][half] = r[j0+jl][ks*32 + q*8 + half*4 ..]
    f32x4 rr[4][2];
    #pragma unroll
    for (int ks = 0; ks < 4; ++ks) {
        rr[ks][0] = *(const f32x4*)(rLDS + jl * 132 + ks * 32 + q * 8);
        rr[ks][1] = *(const f32x4*)(rLDS + jl * 132 + ks * 32 + q * 8 + 4);
    }
    // W2 B-fragments in registers
    bf16_8 bfr[4][4];
    #pragma unroll
    for (int ks = 0; ks < 4; ++ks)
        #pragma unroll
        for (int nt = 0; nt < 4; ++nt)
            bfr[ks][nt] = *((const bf16_8*)frag + (ks * 4 + nt) * 64 + lane);
    // epilogue constants for this lane's g-columns
    float b2v[4], w3v[4];
    #pragma unroll
    for (int nt = 0; nt < 4; ++nt) {
        b2v[nt] = b2[nt * 16 + jl];
        w3v[nt] = W3[nt * 16 + jl];
    }
    const float b3v = b3[0];

    const float* arow = arb + (size_t)(i0 + w * 16) * AR_STRIDE;

    for (int mt = 0; mt < 16; ++mt) {
        const int i = i0 + w * 16 + mt;
        // b2 folded into accumulator init (C cols are g-constant per lane)
        f32x4 acc[4];
        #pragma unroll
        for (int nt = 0; nt < 4; ++nt) {
            f32x4 z = {b2v[nt], b2v[nt], b2v[nt], b2v[nt]};
            acc[nt] = z;
        }
        #pragma unroll
        for (int ks = 0; ks < 4; ++ks) {
            // a' from global: 16-lane broadcast per q-group, L1/L2 resident
            f32x4 a0 = *(const f32x4*)(arow + mt * AR_STRIDE + ks * 32 + q * 8);
            f32x4 a1 = *(const f32x4*)(arow + mt * AR_STRIDE + ks * 32 + q * 8 + 4);
            bf16_8 af;
            #pragma unroll
            for (int e = 0; e < 4; ++e) {
                af[e]     = (__bf16)fmaxf(rr[ks][0][e] + a0[e], 0.f);
                af[4 + e] = (__bf16)fmaxf(rr[ks][1][e] + a1[e], 0.f);
            }
            #pragma unroll
            for (int nt = 0; nt < 4; ++nt)
                acc[nt] = __builtin_amdgcn_mfma_f32_16x16x32_bf16(
                    af, bfr[ks][nt], acc[nt], 0, 0, 0);
        }
        // epilogue: relu(acc) . W3 (b2 already inside acc), DPP row reduce
        float s0 = 0.f, s1 = 0.f, s2 = 0.f, s3 = 0.f;
        #pragma unroll
        for (int nt = 0; nt < 4; ++nt) {
            s0 = fmaf(fmaxf(acc[nt][0], 0.f), w3v[nt], s0);
            s1 = fmaf(fmaxf(acc[nt][1], 0.f), w3v[nt], s1);
            s2 = fmaf(fmaxf(acc[nt][2], 0.f), w3v[nt], s2);
            s3 = fmaf(fmaxf(acc[nt][3], 0.f), w3v[nt], s3);
        }
        s0 = row16_reduce(s0);
        s1 = row16_reduce(s1);
        s2 = row16_reduce(s2);
        s3 = row16_reduce(s3);
        // D row = q*4 + reg  ->  j = j0 + q*4 + reg. Lanes with jl<4 store reg=jl.
        if (jl < 4) {
            int j = j0 + q * 4 + jl;
            float val = (jl == 0) ? s0 : (jl == 1) ? s1 : (jl == 2) ? s2 : s3;
            float res = (j > i) ? (val + b3v) : 0.f;
            outb[i * N_TOK + j] = res;
        }
    }
}

extern "C" void kernel_launch(void* const* d_in, const int* in_sizes, int n_in,
                              void* d_out, int out_size, void* d_ws, size_t ws_size,
                              hipStream_t stream) {
    const float* x  = (const float*)d_in[0];
    const float* W1 = (const float*)d_in[1];
    const float* b1 = (const float*)d_in[2];
    const float* W2 = (const float*)d_in[3];
    const float* b2 = (const float*)d_in[4];
    const float* W3 = (const float*)d_in[5];
    const float* b3 = (const float*)d_in[6];
    float* out = (float*)d_out;

    float* ar = (float*)d_ws;                                    // 2 MB
    __bf16* frag = (__bf16*)((char*)d_ws + AR_BYTES);            // 16 KB

    prep_ar_kernel<<<dim3(64, 4), 256, 0, stream>>>(x, W1, b1, ar);
    prep_frags_kernel<<<dim3(4), 256, 0, stream>>>(W2, frag);
    pair_mlp_kernel<<<dim3(64, 16, 2), 256, 0, stream>>>(ar, frag, b2, W3, b3, out);
}

// Round 4
// 116.746 us; speedup vs baseline: 1.1864x; 1.1864x over previous
//
#include <hip/hip_runtime.h>
#include <hip/hip_bf16.h>

typedef _Float16 f16x8 __attribute__((ext_vector_type(8)));
typedef _Float16 f16x4 __attribute__((ext_vector_type(4)));
typedef float    f32x4 __attribute__((ext_vector_type(4)));

#define N_TOK 1024
#define C_IN  128
#define H1D   128
#define H2D   64
#define NBAT  2
#define AR_STRIDE 256   // fp16 elements per row: [0:128)=a'(+b1), [128:256)=r
#define AR_BYTES (NBAT * N_TOK * AR_STRIDE * 2)

// ---------------------------------------------------------------------------
// Kernel 1: ar[m][h'] (fp16) for m in [0,2048), h' in [0,256):
//   h' <  128 : a'[m][h'] = x[m] @ W1[0:128, h']  + b1[h']   (b1 folded in)
//   h' >= 128 : r [m][h'-128] = x[m] @ W1[128:256, h'-128]
// fp32 accumulate, fp16 store.
// ---------------------------------------------------------------------------
__global__ __launch_bounds__(256) void prep_ar_kernel(
    const float* __restrict__ x, const float* __restrict__ W1,
    const float* __restrict__ b1, _Float16* __restrict__ ar)
{
    const int m0 = blockIdx.x * 32;
    const int h0 = blockIdx.y * 64;
    __shared__ float xs[32 * 132];
    __shared__ float wsh[128 * 64];
    const int t = threadIdx.x;

    #pragma unroll
    for (int it = 0; it < 4; ++it) {
        int f = t + it * 256;
        int row = f >> 5, c4 = f & 31;
        f32x4 v = *(const f32x4*)(x + (m0 + row) * C_IN + c4 * 4);
        *(f32x4*)(xs + row * 132 + c4 * 4) = v;
    }
    const float* wsrc = (h0 < 128) ? (W1 + h0) : (W1 + 128 * H1D + (h0 - 128));
    #pragma unroll
    for (int it = 0; it < 8; ++it) {
        int f = t + it * 256;
        int k = f >> 4, c4 = f & 15;
        f32x4 v = *(const f32x4*)(wsrc + k * H1D + c4 * 4);
        *(f32x4*)(wsh + k * 64 + c4 * 4) = v;
    }
    __syncthreads();

    const int tx = t & 15, ty = t >> 4;
    const int r0 = ty * 2, r1 = r0 + 1;
    float acc0[4] = {0.f, 0.f, 0.f, 0.f};
    float acc1[4] = {0.f, 0.f, 0.f, 0.f};
    #pragma unroll 4
    for (int k = 0; k < 128; ++k) {
        f32x4 w = *(const f32x4*)(wsh + k * 64 + tx * 4);
        float x0 = xs[r0 * 132 + k];
        float x1 = xs[r1 * 132 + k];
        #pragma unroll
        for (int c = 0; c < 4; ++c) {
            acc0[c] = fmaf(x0, w[c], acc0[c]);
            acc1[c] = fmaf(x1, w[c], acc1[c]);
        }
    }
    f32x4 bv = {0.f, 0.f, 0.f, 0.f};
    if (h0 < 128) bv = *(const f32x4*)(b1 + h0 + tx * 4);
    f16x4 o0, o1;
    #pragma unroll
    for (int c = 0; c < 4; ++c) {
        o0[c] = (_Float16)(acc0[c] + bv[c]);
        o1[c] = (_Float16)(acc1[c] + bv[c]);
    }
    *(f16x4*)(ar + (size_t)(m0 + r0) * AR_STRIDE + h0 + tx * 4) = o0;
    *(f16x4*)(ar + (size_t)(m0 + r1) * AR_STRIDE + h0 + tx * 4) = o1;
}

// ---------------------------------------------------------------------------
// Kernel 2: W2 (fp32 [128][64]) -> fp16 B-fragments for mfma_f32_16x16x32_f16
// frag layout: [f = ks*4+nt][lane][jj]  with  k = ks*32 + (lane>>4)*8 + jj,
//                                            g = nt*16 + (lane&15)
// ---------------------------------------------------------------------------
__global__ __launch_bounds__(256) void prep_frags_kernel(
    const float* __restrict__ W2, _Float16* __restrict__ frag)
{
    int e = blockIdx.x * 256 + threadIdx.x;  // 0..1023
    int f = e >> 6, l = e & 63;
    int ks = f >> 2, nt = f & 3;
    int kbase = ks * 32 + (l >> 4) * 8;
    int g = nt * 16 + (l & 15);
    f16x8 v;
    #pragma unroll
    for (int jj = 0; jj < 8; ++jj)
        v[jj] = (_Float16)(W2[(kbase + jj) * H2D + g]);
    *(f16x8*)(frag + e * 8) = v;
}

// DPP butterfly add over the 16-lane DPP row (reduction over jl in [0,16)).
template <int CTRL>
__device__ __forceinline__ float dpp_add(float s) {
    int t = __builtin_amdgcn_update_dpp(0, __builtin_bit_cast(int, s),
                                        CTRL, 0xF, 0xF, true);
    return s + __builtin_bit_cast(float, t);
}
__device__ __forceinline__ float row16_reduce(float s) {
    s = dpp_add<0xB1>(s);   // quad_perm [1,0,3,2]  : xor 1
    s = dpp_add<0x4E>(s);   // quad_perm [2,3,0,1]  : xor 2
    s = dpp_add<0x141>(s);  // row_half_mirror
    s = dpp_add<0x140>(s);  // row_mirror
    return s;
}

// ---------------------------------------------------------------------------
// Kernel 3: pair-MLP. Block = 16 j x 16 i tile, 4 waves; wave w owns i-rows
// i0+w*4 .. +3. NO LDS, no barriers, no shuffles: r-frags + W2-frags +
// epilogue consts live in registers (one-time load), a'-frags double-buffered
// from global (L1/L2-hot) one m-tile ahead. Inner math is packed fp16.
// ---------------------------------------------------------------------------
__global__ __launch_bounds__(256) void pair_mlp_kernel(
    const _Float16* __restrict__ ar, const _Float16* __restrict__ frag,
    const float* __restrict__ b2, const float* __restrict__ W3,
    const float* __restrict__ b3, float* __restrict__ out)
{
    const int tj = blockIdx.x, ti = blockIdx.y, b = blockIdx.z;
    const int j0 = tj * 16, i0 = ti * 16;
    const int t = threadIdx.x;
    float* outb = out + (size_t)b * N_TOK * N_TOK;

    if (tj < ti) {
        // fully masked tile: write zeros (out is poisoned 0xAA)
        outb[(i0 + (t >> 4)) * N_TOK + j0 + (t & 15)] = 0.f;
        return;
    }

    const int lane = t & 63, w = t >> 6;
    const int q = lane >> 4, jl = lane & 15;
    const _Float16* arb = ar + (size_t)b * N_TOK * AR_STRIDE;

    // r-frags: r[j0+jl][ks*32 + q*8 ..+7], one-time
    f16x8 rr[4];
    {
        const _Float16* rbase = arb + (size_t)(j0 + jl) * AR_STRIDE + 128 + q * 8;
        #pragma unroll
        for (int ks = 0; ks < 4; ++ks)
            rr[ks] = *(const f16x8*)(rbase + ks * 32);
    }
    // W2 B-fragments, one-time (same addresses for every wave -> L1 hits)
    f16x8 bfr[4][4];
    #pragma unroll
    for (int ks = 0; ks < 4; ++ks)
        #pragma unroll
        for (int nt = 0; nt < 4; ++nt)
            bfr[ks][nt] = *((const f16x8*)frag + (ks * 4 + nt) * 64 + lane);
    // epilogue constants for this lane's g-columns
    float b2v[4], w3v[4];
    #pragma unroll
    for (int nt = 0; nt < 4; ++nt) {
        b2v[nt] = b2[nt * 16 + jl];
        w3v[nt] = W3[nt * 16 + jl];
    }
    const float b3v = b3[0];

    // a'-frag double buffer: row i0+w*4+mt, chunk ks*32 + q*8
    const _Float16* abase = arb + (size_t)(i0 + w * 4) * AR_STRIDE + q * 8;
    f16x8 abuf[2][4];
    #pragma unroll
    for (int ks = 0; ks < 4; ++ks)
        abuf[0][ks] = *(const f16x8*)(abase + ks * 32);

    const f16x8 zz = {0, 0, 0, 0, 0, 0, 0, 0};

    #pragma unroll
    for (int mt = 0; mt < 4; ++mt) {
        const int cur = mt & 1;
        if (mt < 3) {
            #pragma unroll
            for (int ks = 0; ks < 4; ++ks)
                abuf[cur ^ 1][ks] =
                    *(const f16x8*)(abase + (mt + 1) * AR_STRIDE + ks * 32);
        }
        const int i = i0 + w * 4 + mt;
        // b2 folded into accumulator init (C cols are g-constant per lane)
        f32x4 acc[4];
        #pragma unroll
        for (int nt = 0; nt < 4; ++nt) {
            f32x4 z = {b2v[nt], b2v[nt], b2v[nt], b2v[nt]};
            acc[nt] = z;
        }
        #pragma unroll
        for (int ks = 0; ks < 4; ++ks) {
            f16x8 h = abuf[cur][ks] + rr[ks];      // v_pk_add_f16 x4
            h = __builtin_elementwise_max(h, zz);  // v_pk_max_f16 x4
            #pragma unroll
            for (int nt = 0; nt < 4; ++nt)
                acc[nt] = __builtin_amdgcn_mfma_f32_16x16x32_f16(
                    h, bfr[ks][nt], acc[nt], 0, 0, 0);
        }
        // epilogue: relu(acc) . W3 (b2 already inside acc), DPP row reduce
        float s0 = 0.f, s1 = 0.f, s2 = 0.f, s3 = 0.f;
        #pragma unroll
        for (int nt = 0; nt < 4; ++nt) {
            s0 = fmaf(fmaxf(acc[nt][0], 0.f), w3v[nt], s0);
            s1 = fmaf(fmaxf(acc[nt][1], 0.f), w3v[nt], s1);
            s2 = fmaf(fmaxf(acc[nt][2], 0.f), w3v[nt], s2);
            s3 = fmaf(fmaxf(acc[nt][3], 0.f), w3v[nt], s3);
        }
        s0 = row16_reduce(s0);
        s1 = row16_reduce(s1);
        s2 = row16_reduce(s2);
        s3 = row16_reduce(s3);
        // D row = q*4 + reg  ->  j = j0 + q*4 + reg. Lanes with jl<4 store reg=jl.
        if (jl < 4) {
            int j = j0 + q * 4 + jl;
            float val = (jl == 0) ? s0 : (jl == 1) ? s1 : (jl == 2) ? s2 : s3;
            float res = (j > i) ? (val + b3v) : 0.f;
            outb[i * N_TOK + j] = res;
        }
    }
}

extern "C" void kernel_launch(void* const* d_in, const int* in_sizes, int n_in,
                              void* d_out, int out_size, void* d_ws, size_t ws_size,
                              hipStream_t stream) {
    const float* x  = (const float*)d_in[0];
    const float* W1 = (const float*)d_in[1];
    const float* b1 = (const float*)d_in[2];
    const float* W2 = (const float*)d_in[3];
    const float* b2 = (const float*)d_in[4];
    const float* W3 = (const float*)d_in[5];
    const float* b3 = (const float*)d_in[6];
    float* out = (float*)d_out;

    _Float16* ar   = (_Float16*)d_ws;                         // 1 MB
    _Float16* frag = (_Float16*)((char*)d_ws + AR_BYTES);     // 8 KB

    prep_ar_kernel<<<dim3(64, 4), 256, 0, stream>>>(x, W1, b1, ar);
    prep_frags_kernel<<<dim3(4), 256, 0, stream>>>(W2, frag);
    pair_mlp_kernel<<<dim3(64, 64, 2), 256, 0, stream>>>(ar, frag, b2, W3, b3, out);
}

// Round 5
// 108.927 us; speedup vs baseline: 1.2715x; 1.0718x over previous
//
#include <hip/hip_runtime.h>
#include <hip/hip_bf16.h>

typedef _Float16 f16x8 __attribute__((ext_vector_type(8)));
typedef _Float16 f16x4 __attribute__((ext_vector_type(4)));
typedef float    f32x4 __attribute__((ext_vector_type(4)));

#define N_TOK 1024
#define C_IN  128
#define H1D   128
#define H2D   64
#define NBAT  2
#define AR_STRIDE 256   // fp16 elements per row: [0:128)=a'(+b1), [128:256)=r
#define AR_BYTES (NBAT * N_TOK * AR_STRIDE * 2)

// ---------------------------------------------------------------------------
// Kernel 1: ar[m][h'] (fp16) for m in [0,2048), h' in [0,256):
//   h' <  128 : a'[m][h'] = x[m] @ W1[0:128, h']  + b1[h']   (b1 folded in)
//   h' >= 128 : r [m][h'-128] = x[m] @ W1[128:256, h'-128]
// ---------------------------------------------------------------------------
__global__ __launch_bounds__(256) void prep_ar_kernel(
    const float* __restrict__ x, const float* __restrict__ W1,
    const float* __restrict__ b1, _Float16* __restrict__ ar)
{
    const int m0 = blockIdx.x * 32;
    const int h0 = blockIdx.y * 64;
    __shared__ float xs[32 * 132];
    __shared__ float wsh[128 * 64];
    const int t = threadIdx.x;

    #pragma unroll
    for (int it = 0; it < 4; ++it) {
        int f = t + it * 256;
        int row = f >> 5, c4 = f & 31;
        f32x4 v = *(const f32x4*)(x + (m0 + row) * C_IN + c4 * 4);
        *(f32x4*)(xs + row * 132 + c4 * 4) = v;
    }
    const float* wsrc = (h0 < 128) ? (W1 + h0) : (W1 + 128 * H1D + (h0 - 128));
    #pragma unroll
    for (int it = 0; it < 8; ++it) {
        int f = t + it * 256;
        int k = f >> 4, c4 = f & 15;
        f32x4 v = *(const f32x4*)(wsrc + k * H1D + c4 * 4);
        *(f32x4*)(wsh + k * 64 + c4 * 4) = v;
    }
    __syncthreads();

    const int tx = t & 15, ty = t >> 4;
    const int r0 = ty * 2, r1 = r0 + 1;
    float acc0[4] = {0.f, 0.f, 0.f, 0.f};
    float acc1[4] = {0.f, 0.f, 0.f, 0.f};
    #pragma unroll 4
    for (int k = 0; k < 128; ++k) {
        f32x4 w = *(const f32x4*)(wsh + k * 64 + tx * 4);
        float x0 = xs[r0 * 132 + k];
        float x1 = xs[r1 * 132 + k];
        #pragma unroll
        for (int c = 0; c < 4; ++c) {
            acc0[c] = fmaf(x0, w[c], acc0[c]);
            acc1[c] = fmaf(x1, w[c], acc1[c]);
        }
    }
    f32x4 bv = {0.f, 0.f, 0.f, 0.f};
    if (h0 < 128) bv = *(const f32x4*)(b1 + h0 + tx * 4);
    f16x4 o0, o1;
    #pragma unroll
    for (int c = 0; c < 4; ++c) {
        o0[c] = (_Float16)(acc0[c] + bv[c]);
        o1[c] = (_Float16)(acc1[c] + bv[c]);
    }
    *(f16x4*)(ar + (size_t)(m0 + r0) * AR_STRIDE + h0 + tx * 4) = o0;
    *(f16x4*)(ar + (size_t)(m0 + r1) * AR_STRIDE + h0 + tx * 4) = o1;
}

// ---------------------------------------------------------------------------
// Kernel 2: W2 (fp32 [128][64]) -> fp16 B-fragments for mfma_f32_16x16x32_f16
// frag layout: [f = ks*4+nt][lane][jj]  with  k = ks*32 + (lane>>4)*8 + jj,
//                                            g = nt*16 + (lane&15)
// ---------------------------------------------------------------------------
__global__ __launch_bounds__(256) void prep_frags_kernel(
    const float* __restrict__ W2, _Float16* __restrict__ frag)
{
    int e = blockIdx.x * 256 + threadIdx.x;  // 0..1023
    int f = e >> 6, l = e & 63;
    int ks = f >> 2, nt = f & 3;
    int kbase = ks * 32 + (l >> 4) * 8;
    int g = nt * 16 + (l & 15);
    f16x8 v;
    #pragma unroll
    for (int jj = 0; jj < 8; ++jj)
        v[jj] = (_Float16)(W2[(kbase + jj) * H2D + g]);
    *(f16x8*)(frag + e * 8) = v;
}

// DPP butterfly add over the 16-lane DPP row (reduction over jl in [0,16)).
template <int CTRL>
__device__ __forceinline__ float dpp_add(float s) {
    int t = __builtin_amdgcn_update_dpp(0, __builtin_bit_cast(int, s),
                                        CTRL, 0xF, 0xF, true);
    return s + __builtin_bit_cast(float, t);
}
__device__ __forceinline__ float row16_reduce(float s) {
    s = dpp_add<0xB1>(s);   // quad_perm [1,0,3,2]  : xor 1
    s = dpp_add<0x4E>(s);   // quad_perm [2,3,0,1]  : xor 2
    s = dpp_add<0x141>(s);  // row_half_mirror
    s = dpp_add<0x140>(s);  // row_mirror
    return s;
}

// ---------------------------------------------------------------------------
// Kernel 3: pair-MLP. Block = 64 i x 16 j, 4 waves; wave w owns i-rows
// i0+w*16 .. +15 (16 m-tiles -> prologue amortized). NO LDS/barriers/shuffles.
// r-frags + W2-frags + consts in registers; a'-frags double-buffered from
// global (L1/L2-hot) one m-tile ahead. Inner math packed fp16, DPP reduce.
// ---------------------------------------------------------------------------
__global__ __launch_bounds__(256) void pair_mlp_kernel(
    const _Float16* __restrict__ ar, const _Float16* __restrict__ frag,
    const float* __restrict__ b2, const float* __restrict__ W3,
    const float* __restrict__ b3, float* __restrict__ out)
{
    const int j0 = blockIdx.x * 16;   // 64 j-tiles
    const int i0 = blockIdx.y * 64;   // 16 i-strips
    const int b  = blockIdx.z;
    const int t  = threadIdx.x;
    float* outb = out + (size_t)b * N_TOK * N_TOK;

    if (j0 + 15 <= i0) {
        // fully masked 64x16 tile: write zeros (out is poisoned 0xAA)
        int row = t >> 2, c4 = t & 3;
        f32x4 z = {0.f, 0.f, 0.f, 0.f};
        *(f32x4*)(outb + (i0 + row) * N_TOK + j0 + c4 * 4) = z;
        return;
    }

    const int lane = t & 63, w = t >> 6;
    const int q = lane >> 4, jl = lane & 15;
    const _Float16* arb = ar + (size_t)b * N_TOK * AR_STRIDE;

    // r-frags: r[j0+jl][ks*32 + q*8 ..+7], one-time
    f16x8 rr[4];
    {
        const _Float16* rbase = arb + (size_t)(j0 + jl) * AR_STRIDE + 128 + q * 8;
        #pragma unroll
        for (int ks = 0; ks < 4; ++ks)
            rr[ks] = *(const f16x8*)(rbase + ks * 32);
    }
    // W2 B-fragments, one-time (same addresses for every wave -> L1 hits)
    f16x8 bfr[4][4];
    #pragma unroll
    for (int ks = 0; ks < 4; ++ks)
        #pragma unroll
        for (int nt = 0; nt < 4; ++nt)
            bfr[ks][nt] = *((const f16x8*)frag + (ks * 4 + nt) * 64 + lane);
    // epilogue constants for this lane's g-columns
    float b2v[4], w3v[4];
    #pragma unroll
    for (int nt = 0; nt < 4; ++nt) {
        b2v[nt] = b2[nt * 16 + jl];
        w3v[nt] = W3[nt * 16 + jl];
    }
    const float b3v = b3[0];

    // a'-frag double buffer: wave's rows start at i0 + w*16
    const _Float16* abase = arb + (size_t)(i0 + w * 16) * AR_STRIDE + q * 8;
    f16x8 abuf[2][4];
    #pragma unroll
    for (int ks = 0; ks < 4; ++ks)
        abuf[0][ks] = *(const f16x8*)(abase + ks * 32);

    const f16x8 zz = {0, 0, 0, 0, 0, 0, 0, 0};

    #pragma unroll 2
    for (int mt = 0; mt < 16; ++mt) {
        const int cur = mt & 1;
        if (mt < 15) {
            #pragma unroll
            for (int ks = 0; ks < 4; ++ks)
                abuf[cur ^ 1][ks] =
                    *(const f16x8*)(abase + (mt + 1) * AR_STRIDE + ks * 32);
        }
        const int i = i0 + w * 16 + mt;
        // b2 folded into accumulator init (C cols are g-constant per lane)
        f32x4 acc[4];
        #pragma unroll
        for (int nt = 0; nt < 4; ++nt) {
            f32x4 z = {b2v[nt], b2v[nt], b2v[nt], b2v[nt]};
            acc[nt] = z;
        }
        #pragma unroll
        for (int ks = 0; ks < 4; ++ks) {
            f16x8 h = abuf[cur][ks] + rr[ks];      // v_pk_add_f16 x4
            h = __builtin_elementwise_max(h, zz);  // v_pk_max_f16 x4
            #pragma unroll
            for (int nt = 0; nt < 4; ++nt)
                acc[nt] = __builtin_amdgcn_mfma_f32_16x16x32_f16(
                    h, bfr[ks][nt], acc[nt], 0, 0, 0);
        }
        // epilogue: relu(acc) . W3 (b2 already inside acc), DPP row reduce
        float s0 = 0.f, s1 = 0.f, s2 = 0.f, s3 = 0.f;
        #pragma unroll
        for (int nt = 0; nt < 4; ++nt) {
            s0 = fmaf(fmaxf(acc[nt][0], 0.f), w3v[nt], s0);
            s1 = fmaf(fmaxf(acc[nt][1], 0.f), w3v[nt], s1);
            s2 = fmaf(fmaxf(acc[nt][2], 0.f), w3v[nt], s2);
            s3 = fmaf(fmaxf(acc[nt][3], 0.f), w3v[nt], s3);
        }
        s0 = row16_reduce(s0);
        s1 = row16_reduce(s1);
        s2 = row16_reduce(s2);
        s3 = row16_reduce(s3);
        // D row = q*4 + reg  ->  j = j0 + q*4 + reg. Lanes with jl<4 store reg=jl.
        if (jl < 4) {
            int j = j0 + q * 4 + jl;
            float val = (jl == 0) ? s0 : (jl == 1) ? s1 : (jl == 2) ? s2 : s3;
            float res = (j > i) ? (val + b3v) : 0.f;
            outb[i * N_TOK + j] = res;
        }
    }
}

extern "C" void kernel_launch(void* const* d_in, const int* in_sizes, int n_in,
                              void* d_out, int out_size, void* d_ws, size_t ws_size,
                              hipStream_t stream) {
    const float* x  = (const float*)d_in[0];
    const float* W1 = (const float*)d_in[1];
    const float* b1 = (const float*)d_in[2];
    const float* W2 = (const float*)d_in[3];
    const float* b2 = (const float*)d_in[4];
    const float* W3 = (const float*)d_in[5];
    const float* b3 = (const float*)d_in[6];
    float* out = (float*)d_out;

    _Float16* ar   = (_Float16*)d_ws;                         // 1 MB
    _Float16* frag = (_Float16*)((char*)d_ws + AR_BYTES);     // 8 KB

    prep_ar_kernel<<<dim3(64, 4), 256, 0, stream>>>(x, W1, b1, ar);
    prep_frags_kernel<<<dim3(4), 256, 0, stream>>>(W2, frag);
    pair_mlp_kernel<<<dim3(64, 16, 2), 256, 0, stream>>>(ar, frag, b2, W3, b3, out);
}

// Round 6
// 99.090 us; speedup vs baseline: 1.3978x; 1.0993x over previous
//
#include <hip/hip_runtime.h>
#include <hip/hip_bf16.h>

typedef _Float16 f16x8 __attribute__((ext_vector_type(8)));
typedef _Float16 f16x4 __attribute__((ext_vector_type(4)));
typedef float    f32x4 __attribute__((ext_vector_type(4)));

#define N_TOK 1024
#define C_IN  128
#define H1D   128
#define H2D   64
#define NBAT  2
#define AR_STRIDE 256   // fp16 elements per row: [0:128)=a'(+b1), [128:256)=r
#define AR_BYTES (NBAT * N_TOK * AR_STRIDE * 2)
#define NWORK 544       // working 64x16 tiles per batch (tj >= 4*ti)
#define NZERO 480       // fully-masked tiles per batch (tj < 4*ti)

// ---------------------------------------------------------------------------
// Kernel 1: ar[m][h'] (fp16) for m in [0,2048), h' in [0,256):
//   h' <  128 : a'[m][h'] = x[m] @ W1[0:128, h']  + b1[h']   (b1 folded in)
//   h' >= 128 : r [m][h'-128] = x[m] @ W1[128:256, h'-128]
// ---------------------------------------------------------------------------
__global__ __launch_bounds__(256) void prep_ar_kernel(
    const float* __restrict__ x, const float* __restrict__ W1,
    const float* __restrict__ b1, _Float16* __restrict__ ar)
{
    const int m0 = blockIdx.x * 32;
    const int h0 = blockIdx.y * 64;
    __shared__ float xs[32 * 132];
    __shared__ float wsh[128 * 64];
    const int t = threadIdx.x;

    #pragma unroll
    for (int it = 0; it < 4; ++it) {
        int f = t + it * 256;
        int row = f >> 5, c4 = f & 31;
        f32x4 v = *(const f32x4*)(x + (m0 + row) * C_IN + c4 * 4);
        *(f32x4*)(xs + row * 132 + c4 * 4) = v;
    }
    const float* wsrc = (h0 < 128) ? (W1 + h0) : (W1 + 128 * H1D + (h0 - 128));
    #pragma unroll
    for (int it = 0; it < 8; ++it) {
        int f = t + it * 256;
        int k = f >> 4, c4 = f & 15;
        f32x4 v = *(const f32x4*)(wsrc + k * H1D + c4 * 4);
        *(f32x4*)(wsh + k * 64 + c4 * 4) = v;
    }
    __syncthreads();

    const int tx = t & 15, ty = t >> 4;
    const int r0 = ty * 2, r1 = r0 + 1;
    float acc0[4] = {0.f, 0.f, 0.f, 0.f};
    float acc1[4] = {0.f, 0.f, 0.f, 0.f};
    #pragma unroll 4
    for (int k = 0; k < 128; ++k) {
        f32x4 w = *(const f32x4*)(wsh + k * 64 + tx * 4);
        float x0 = xs[r0 * 132 + k];
        float x1 = xs[r1 * 132 + k];
        #pragma unroll
        for (int c = 0; c < 4; ++c) {
            acc0[c] = fmaf(x0, w[c], acc0[c]);
            acc1[c] = fmaf(x1, w[c], acc1[c]);
        }
    }
    f32x4 bv = {0.f, 0.f, 0.f, 0.f};
    if (h0 < 128) bv = *(const f32x4*)(b1 + h0 + tx * 4);
    f16x4 o0, o1;
    #pragma unroll
    for (int c = 0; c < 4; ++c) {
        o0[c] = (_Float16)(acc0[c] + bv[c]);
        o1[c] = (_Float16)(acc1[c] + bv[c]);
    }
    *(f16x4*)(ar + (size_t)(m0 + r0) * AR_STRIDE + h0 + tx * 4) = o0;
    *(f16x4*)(ar + (size_t)(m0 + r1) * AR_STRIDE + h0 + tx * 4) = o1;
}

// ---------------------------------------------------------------------------
// Kernel 2: W2 (fp32 [128][64]) -> fp16 B-fragments for mfma_f32_16x16x32_f16
// frag layout: [f = ks*4+nt][lane][jj]  with  k = ks*32 + (lane>>4)*8 + jj,
//                                            g = nt*16 + (lane&15)
// ---------------------------------------------------------------------------
__global__ __launch_bounds__(256) void prep_frags_kernel(
    const float* __restrict__ W2, _Float16* __restrict__ frag)
{
    int e = blockIdx.x * 256 + threadIdx.x;  // 0..1023
    int f = e >> 6, l = e & 63;
    int ks = f >> 2, nt = f & 3;
    int kbase = ks * 32 + (l >> 4) * 8;
    int g = nt * 16 + (l & 15);
    f16x8 v;
    #pragma unroll
    for (int jj = 0; jj < 8; ++jj)
        v[jj] = (_Float16)(W2[(kbase + jj) * H2D + g]);
    *(f16x8*)(frag + e * 8) = v;
}

// DPP butterfly add over the 16-lane DPP row (reduction over jl in [0,16)).
template <int CTRL>
__device__ __forceinline__ float dpp_add(float s) {
    int t = __builtin_amdgcn_update_dpp(0, __builtin_bit_cast(int, s),
                                        CTRL, 0xF, 0xF, true);
    return s + __builtin_bit_cast(float, t);
}
__device__ __forceinline__ float row16_reduce(float s) {
    s = dpp_add<0xB1>(s);   // quad_perm [1,0,3,2]  : xor 1
    s = dpp_add<0x4E>(s);   // quad_perm [2,3,0,1]  : xor 2
    s = dpp_add<0x141>(s);  // row_half_mirror
    s = dpp_add<0x140>(s);  // row_mirror
    return s;
}

// ---------------------------------------------------------------------------
// Kernel 3: pair-MLP, working-tiles-only grid.
// blockIdx.x < NWORK : compute 64i x 16j tile (ti,tj from closed-form map).
// else               : zero-fill a fully-masked tile.
// a' staged in LDS once per block (16 KB fp16); in-loop = 4 ds_read_b128
// (broadcast, conflict-free) double-buffered one m-tile ahead. r-frags,
// W2-frags, consts in registers. Packed fp16 math, DPP reduce. No VMEM loads
// in the loop.
// ---------------------------------------------------------------------------
__global__ __launch_bounds__(256) void pair_mlp_kernel(
    const _Float16* __restrict__ ar, const _Float16* __restrict__ frag,
    const float* __restrict__ b2, const float* __restrict__ W3,
    const float* __restrict__ b3, float* __restrict__ out)
{
    const int b  = blockIdx.z;
    const int bx = blockIdx.x;
    const int t  = threadIdx.x;
    float* outb = out + (size_t)b * N_TOK * N_TOK;

    if (bx >= NWORK) {
        // fully-masked tile (tj < 4*ti): write zeros (out is poisoned 0xAA)
        int zb = bx - NWORK;
        int ti = 1;
        #pragma unroll
        for (int tt = 2; tt <= 15; ++tt)
            if (zb >= 2 * tt * (tt - 1)) ti = tt;
        int tj = zb - 2 * ti * (ti - 1);
        int i0 = ti * 64, j0 = tj * 16;
        int row = t >> 2, c4 = t & 3;
        f32x4 z = {0.f, 0.f, 0.f, 0.f};
        *(f32x4*)(outb + (i0 + row) * N_TOK + j0 + c4 * 4) = z;
        return;
    }

    // working tile: row ti has tj in [4*ti, 63], prefix(ti) = 66*ti - 2*ti^2
    int ti = 0;
    #pragma unroll
    for (int tt = 1; tt <= 15; ++tt)
        if (bx >= 66 * tt - 2 * tt * tt) ti = tt;
    const int tj = 4 * ti + (bx - (66 * ti - 2 * ti * ti));
    const int i0 = ti * 64, j0 = tj * 16;

    __shared__ _Float16 aLDS[64 * 128];  // a' rows i0..i0+63, fp16, 16 KB
    const _Float16* arb = ar + (size_t)b * N_TOK * AR_STRIDE;

    // stage a' tile: 64 rows x 256 B = 1024 16B-chunks, 4 per thread
    #pragma unroll
    for (int it = 0; it < 4; ++it) {
        int c = t + it * 256;
        int row = c >> 4, cc = c & 15;
        *(f16x8*)(aLDS + row * 128 + cc * 8) =
            *(const f16x8*)(arb + (size_t)(i0 + row) * AR_STRIDE + cc * 8);
    }

    const int lane = t & 63, w = t >> 6;
    const int q = lane >> 4, jl = lane & 15;

    // r-frags: r[j0+jl][ks*32 + q*8 ..+7], one-time from global
    f16x8 rr[4];
    {
        const _Float16* rbase = arb + (size_t)(j0 + jl) * AR_STRIDE + 128 + q * 8;
        #pragma unroll
        for (int ks = 0; ks < 4; ++ks)
            rr[ks] = *(const f16x8*)(rbase + ks * 32);
    }
    // W2 B-fragments, one-time (hot in L1/L2 across blocks)
    f16x8 bfr[4][4];
    #pragma unroll
    for (int ks = 0; ks < 4; ++ks)
        #pragma unroll
        for (int nt = 0; nt < 4; ++nt)
            bfr[ks][nt] = *((const f16x8*)frag + (ks * 4 + nt) * 64 + lane);
    // epilogue constants for this lane's g-columns
    float b2v[4], w3v[4];
    #pragma unroll
    for (int nt = 0; nt < 4; ++nt) {
        b2v[nt] = b2[nt * 16 + jl];
        w3v[nt] = W3[nt * 16 + jl];
    }
    const float b3v = b3[0];

    __syncthreads();

    // a'-frag double buffer from LDS: wave's rows start at li0 = w*16
    const _Float16* abase = aLDS + (w * 16) * 128 + q * 8;
    f16x8 abuf[2][4];
    #pragma unroll
    for (int ks = 0; ks < 4; ++ks)
        abuf[0][ks] = *(const f16x8*)(abase + ks * 32);

    const f16x8 zz = {0, 0, 0, 0, 0, 0, 0, 0};

    #pragma unroll 2
    for (int mt = 0; mt < 16; ++mt) {
        const int cur = mt & 1;
        if (mt < 15) {
            #pragma unroll
            for (int ks = 0; ks < 4; ++ks)
                abuf[cur ^ 1][ks] =
                    *(const f16x8*)(abase + (mt + 1) * 128 + ks * 32);
        }
        const int i = i0 + w * 16 + mt;
        // b2 folded into accumulator init (C cols are g-constant per lane)
        f32x4 acc[4];
        #pragma unroll
        for (int nt = 0; nt < 4; ++nt) {
            f32x4 z = {b2v[nt], b2v[nt], b2v[nt], b2v[nt]};
            acc[nt] = z;
        }
        #pragma unroll
        for (int ks = 0; ks < 4; ++ks) {
            f16x8 h = abuf[cur][ks] + rr[ks];      // v_pk_add_f16 x4
            h = __builtin_elementwise_max(h, zz);  // v_pk_max_f16 x4
            #pragma unroll
            for (int nt = 0; nt < 4; ++nt)
                acc[nt] = __builtin_amdgcn_mfma_f32_16x16x32_f16(
                    h, bfr[ks][nt], acc[nt], 0, 0, 0);
        }
        // epilogue: relu(acc) . W3 (b2 already inside acc), DPP row reduce
        float s0 = 0.f, s1 = 0.f, s2 = 0.f, s3 = 0.f;
        #pragma unroll
        for (int nt = 0; nt < 4; ++nt) {
            s0 = fmaf(fmaxf(acc[nt][0], 0.f), w3v[nt], s0);
            s1 = fmaf(fmaxf(acc[nt][1], 0.f), w3v[nt], s1);
            s2 = fmaf(fmaxf(acc[nt][2], 0.f), w3v[nt], s2);
            s3 = fmaf(fmaxf(acc[nt][3], 0.f), w3v[nt], s3);
        }
        s0 = row16_reduce(s0);
        s1 = row16_reduce(s1);
        s2 = row16_reduce(s2);
        s3 = row16_reduce(s3);
        // D row = q*4 + reg  ->  j = j0 + q*4 + reg. Lanes with jl<4 store reg=jl.
        if (jl < 4) {
            int j = j0 + q * 4 + jl;
            float val = (jl == 0) ? s0 : (jl == 1) ? s1 : (jl == 2) ? s2 : s3;
            float res = (j > i) ? (val + b3v) : 0.f;
            outb[i * N_TOK + j] = res;
        }
    }
}

extern "C" void kernel_launch(void* const* d_in, const int* in_sizes, int n_in,
                              void* d_out, int out_size, void* d_ws, size_t ws_size,
                              hipStream_t stream) {
    const float* x  = (const float*)d_in[0];
    const float* W1 = (const float*)d_in[1];
    const float* b1 = (const float*)d_in[2];
    const float* W2 = (const float*)d_in[3];
    const float* b2 = (const float*)d_in[4];
    const float* W3 = (const float*)d_in[5];
    const float* b3 = (const float*)d_in[6];
    float* out = (float*)d_out;

    _Float16* ar   = (_Float16*)d_ws;                         // 1 MB
    _Float16* frag = (_Float16*)((char*)d_ws + AR_BYTES);     // 8 KB

    prep_ar_kernel<<<dim3(64, 4), 256, 0, stream>>>(x, W1, b1, ar);
    prep_frags_kernel<<<dim3(4), 256, 0, stream>>>(W2, frag);
    pair_mlp_kernel<<<dim3(NWORK + NZERO, 1, 2), 256, 0, stream>>>(
        ar, frag, b2, W3, b3, out);
}